// Round 3
// baseline (137.927 us; speedup 1.0000x reference)
//
#include <hip/hip_runtime.h>

#define Bv 4
#define Vv 50000
#define Cv 160

// Kernel 1: per-(b,c) affine table A[b][c][12]:
//   A[0..8]  = R row-major (rows b1,b2,b3)
//   A[9..11] = center + V_nodes - R*center
// so out[b,v,:] = M·x_v + t with [M|t] = sum_c W[v,c]*A[b,c,:]
__global__ void precompute_A(const float* __restrict__ X,
                             const float* __restrict__ Vn,
                             const float* __restrict__ r6,
                             const int* __restrict__ idx,
                             float* __restrict__ A) {
    int i = blockIdx.x * blockDim.x + threadIdx.x;
    if (i >= Bv * Cv) return;
    int b = i / Cv, c = i % Cv;

    const float* d6 = r6 + (size_t)(b * Cv + c) * 6;
    float a1x = d6[0], a1y = d6[1], a1z = d6[2];
    float a2x = d6[3], a2y = d6[4], a2z = d6[5];

    float n1 = fmaxf(sqrtf(a1x*a1x + a1y*a1y + a1z*a1z), 1e-8f);
    float b1x = a1x / n1, b1y = a1y / n1, b1z = a1z / n1;

    float d = b1x*a2x + b1y*a2y + b1z*a2z;
    float px = a2x - d*b1x, py = a2y - d*b1y, pz = a2z - d*b1z;
    float n2 = fmaxf(sqrtf(px*px + py*py + pz*pz), 1e-8f);
    float b2x = px / n2, b2y = py / n2, b2z = pz / n2;

    float b3x = b1y*b2z - b1z*b2y;
    float b3y = b1z*b2x - b1x*b2z;
    float b3z = b1x*b2y - b1y*b2x;

    int iv = idx[c];
    const float* xc = X + ((size_t)b * Vv + iv) * 3;
    float cx = xc[0], cy = xc[1], cz = xc[2];
    const float* vn = Vn + (size_t)(b * Cv + c) * 3;
    float vx = vn[0], vy = vn[1], vz = vn[2];

    float* Ao = A + (size_t)(b * Cv + c) * 12;
    Ao[0] = b1x; Ao[1] = b1y; Ao[2] = b1z;
    Ao[3] = b2x; Ao[4] = b2y; Ao[5] = b2z;
    Ao[6] = b3x; Ao[7] = b3y; Ao[8] = b3z;
    Ao[9]  = cx + vx - (b1x*cx + b1y*cy + b1z*cz);
    Ao[10] = cy + vy - (b2x*cx + b2y*cy + b2z*cz);
    Ao[11] = cz + vz - (b3x*cx + b3y*cy + b3z*cz);
}

// Kernel 2: block = 128 threads = 2 waves over the same 64 vertices.
// Wave w handles batches {2w, 2w+1}: one LDS read of W[v,c] feeds 24 FMAs.
// A addresses are wave-uniform -> scalar (s_load) path.
#define WSTRIDE 161  // odd stride: bank = (lane + c) % 32 -> 2 lanes/bank (free)
__global__ __launch_bounds__(128) void deform_main(const float* __restrict__ X,
                                                   const float* __restrict__ W,
                                                   const float* __restrict__ A,
                                                   float* __restrict__ out) {
    __shared__ float Wl[64 * WSTRIDE];  // 41.2 KB -> 3 blocks/CU

    const int tid = threadIdx.x;
    const int v0 = blockIdx.x * 64;
    const int nrows = min(64, Vv - v0);

    // Stage W rows [v0, v0+nrows): coalesced float4 reads (rows 640 B, 16B-aligned).
    for (int i4 = tid; i4 < nrows * 40; i4 += 128) {
        int v  = i4 / 40;
        int c4 = i4 % 40;
        float4 q = ((const float4*)(W + (size_t)(v0 + v) * Cv))[c4];
        float* dst = &Wl[v * WSTRIDE + c4 * 4];
        dst[0] = q.x; dst[1] = q.y; dst[2] = q.z; dst[3] = q.w;
    }
    __syncthreads();

    const int lane = tid & 63;
    const int wv = __builtin_amdgcn_readfirstlane(tid >> 6);  // 0 or 1, wave-uniform
    const int b0 = 2 * wv, b1 = 2 * wv + 1;

    const int v = v0 + lane;
    const bool valid = (v < Vv);
    const int vc = valid ? v : (Vv - 1);

    const float* xp0 = X + ((size_t)b0 * Vv + vc) * 3;
    const float* xp1 = X + ((size_t)b1 * Vv + vc) * 3;
    float x00 = xp0[0], x01 = xp0[1], x02 = xp0[2];
    float x10 = xp1[0], x11 = xp1[1], x12 = xp1[2];

    const float* __restrict__ Ab0 = A + (size_t)b0 * Cv * 12;  // wave-uniform
    const float* __restrict__ Ab1 = A + (size_t)b1 * Cv * 12;
    const float* wrow = &Wl[lane * WSTRIDE];

    float acc0[12], acc1[12];
#pragma unroll
    for (int j = 0; j < 12; ++j) { acc0[j] = 0.0f; acc1[j] = 0.0f; }

#pragma unroll 2
    for (int c = 0; c < Cv; ++c) {
        float w = wrow[c];
        const float* a0 = Ab0 + c * 12;
        const float* a1 = Ab1 + c * 12;
#pragma unroll
        for (int j = 0; j < 12; ++j) acc0[j] = fmaf(w, a0[j], acc0[j]);
#pragma unroll
        for (int j = 0; j < 12; ++j) acc1[j] = fmaf(w, a1[j], acc1[j]);
    }

    if (valid) {
        float* op0 = out + ((size_t)b0 * Vv + v) * 3;
        op0[0] = acc0[0]*x00 + acc0[1]*x01 + acc0[2]*x02 + acc0[9];
        op0[1] = acc0[3]*x00 + acc0[4]*x01 + acc0[5]*x02 + acc0[10];
        op0[2] = acc0[6]*x00 + acc0[7]*x01 + acc0[8]*x02 + acc0[11];
        float* op1 = out + ((size_t)b1 * Vv + v) * 3;
        op1[0] = acc1[0]*x10 + acc1[1]*x11 + acc1[2]*x12 + acc1[9];
        op1[1] = acc1[3]*x10 + acc1[4]*x11 + acc1[5]*x12 + acc1[10];
        op1[2] = acc1[6]*x10 + acc1[7]*x11 + acc1[8]*x12 + acc1[11];
    }
}

extern "C" void kernel_launch(void* const* d_in, const int* in_sizes, int n_in,
                              void* d_out, int out_size, void* d_ws, size_t ws_size,
                              hipStream_t stream) {
    const float* X   = (const float*)d_in[0];  // (B,V,3) fp32
    const float* Vn  = (const float*)d_in[1];  // (B,C,3) fp32
    const float* r6  = (const float*)d_in[2];  // (B,C,6) fp32
    const float* W   = (const float*)d_in[3];  // (V,C)   fp32
    const int*   idx = (const int*)d_in[4];    // (C,)    int32
    float* out = (float*)d_out;                // (B,V,3) fp32
    float* A = (float*)d_ws;                   // B*C*12 floats = 30720 B

    precompute_A<<<(Bv * Cv + 255) / 256, 256, 0, stream>>>(X, Vn, r6, idx, A);
    deform_main<<<(Vv + 63) / 64, 128, 0, stream>>>(X, W, A, out);
}

// Round 4
// 101.162 us; speedup vs baseline: 1.3634x; 1.3634x over previous
//
#include <hip/hip_runtime.h>

#define Bv 4
#define Vv 50000
#define Cv 160

// Kernel 1: per-(b,c) affine table A[b][c][12]:
//   A[0..8]  = R row-major (rows b1,b2,b3)
//   A[9..11] = center + V_nodes - R*center
// so out[b,v,:] = M·x_v + t with [M|t] = sum_c W[v,c]*A[b,c,:]
__global__ void precompute_A(const float* __restrict__ X,
                             const float* __restrict__ Vn,
                             const float* __restrict__ r6,
                             const int* __restrict__ idx,
                             float* __restrict__ A) {
    int i = blockIdx.x * blockDim.x + threadIdx.x;
    if (i >= Bv * Cv) return;
    int b = i / Cv, c = i % Cv;

    const float* d6 = r6 + (size_t)(b * Cv + c) * 6;
    float a1x = d6[0], a1y = d6[1], a1z = d6[2];
    float a2x = d6[3], a2y = d6[4], a2z = d6[5];

    float n1 = fmaxf(sqrtf(a1x*a1x + a1y*a1y + a1z*a1z), 1e-8f);
    float b1x = a1x / n1, b1y = a1y / n1, b1z = a1z / n1;

    float d = b1x*a2x + b1y*a2y + b1z*a2z;
    float px = a2x - d*b1x, py = a2y - d*b1y, pz = a2z - d*b1z;
    float n2 = fmaxf(sqrtf(px*px + py*py + pz*pz), 1e-8f);
    float b2x = px / n2, b2y = py / n2, b2z = pz / n2;

    float b3x = b1y*b2z - b1z*b2y;
    float b3y = b1z*b2x - b1x*b2z;
    float b3z = b1x*b2y - b1y*b2x;

    int iv = idx[c];
    const float* xc = X + ((size_t)b * Vv + iv) * 3;
    float cx = xc[0], cy = xc[1], cz = xc[2];
    const float* vn = Vn + (size_t)(b * Cv + c) * 3;
    float vx = vn[0], vy = vn[1], vz = vn[2];

    float* Ao = A + (size_t)(b * Cv + c) * 12;
    Ao[0] = b1x; Ao[1] = b1y; Ao[2] = b1z;
    Ao[3] = b2x; Ao[4] = b2y; Ao[5] = b2z;
    Ao[6] = b3x; Ao[7] = b3y; Ao[8] = b3z;
    Ao[9]  = cx + vx - (b1x*cx + b1y*cy + b1z*cz);
    Ao[10] = cy + vy - (b2x*cx + b2y*cy + b2z*cz);
    Ao[11] = cz + vz - (b3x*cx + b3y*cy + b3z*cz);
}

// Kernel 2: block = 256 threads = 4 waves over the same 64 vertices;
// wave w handles batch b=w. NO LDS, NO barriers, NO scalar loads in the
// hot loop: W and A both come in as global_load_dwordx4 (vmcnt-only,
// FIFO-pipelined). A's address is wave-uniform -> SGPR base + imm offset,
// L1 broadcast. The 4 waves of a block share the same 64 W rows (L1/L2 reuse).
__global__ __launch_bounds__(256) void deform_main(const float* __restrict__ X,
                                                   const float* __restrict__ W,
                                                   const float* __restrict__ A,
                                                   float* __restrict__ out) {
    const int tid  = threadIdx.x;
    const int lane = tid & 63;
    const int b    = __builtin_amdgcn_readfirstlane(tid >> 6);  // wave-uniform batch
    const int v0   = blockIdx.x * 64;
    const int v    = v0 + lane;
    const bool valid = (v < Vv);
    const int vc   = valid ? v : (Vv - 1);

    const float4* __restrict__ Wrow = (const float4*)(W + (size_t)vc * Cv);  // 40 x float4
    const float4* __restrict__ A4   = (const float4*)(A + (size_t)b * Cv * 12);

    const float* xp = X + ((size_t)b * Vv + vc) * 3;
    float x0 = xp[0], x1 = xp[1], x2 = xp[2];

    float acc[12];
#pragma unroll
    for (int j = 0; j < 12; ++j) acc[j] = 0.0f;

#pragma unroll 2
    for (int c4 = 0; c4 < Cv / 4; ++c4) {
        float4 wq = Wrow[c4];
        const float wj[4] = {wq.x, wq.y, wq.z, wq.w};
#pragma unroll
        for (int j = 0; j < 4; ++j) {
            int c = c4 * 4 + j;
            float4 a0 = A4[c * 3 + 0];
            float4 a1 = A4[c * 3 + 1];
            float4 a2 = A4[c * 3 + 2];
            float w = wj[j];
            acc[0]  = fmaf(w, a0.x, acc[0]);
            acc[1]  = fmaf(w, a0.y, acc[1]);
            acc[2]  = fmaf(w, a0.z, acc[2]);
            acc[3]  = fmaf(w, a0.w, acc[3]);
            acc[4]  = fmaf(w, a1.x, acc[4]);
            acc[5]  = fmaf(w, a1.y, acc[5]);
            acc[6]  = fmaf(w, a1.z, acc[6]);
            acc[7]  = fmaf(w, a1.w, acc[7]);
            acc[8]  = fmaf(w, a2.x, acc[8]);
            acc[9]  = fmaf(w, a2.y, acc[9]);
            acc[10] = fmaf(w, a2.z, acc[10]);
            acc[11] = fmaf(w, a2.w, acc[11]);
        }
    }

    if (valid) {
        // acc layout per c: [0..3]=(M00,M01,M02,T0? no) — A rows are
        // [b1(3) b2(3) b3(3) T(3)] flattened; float4 view groups as
        // a0=(M00,M01,M02,M10) a1=(M11,M12,M20,M21) a2=(M22,T0,T1,T2)
        float o0 = acc[0]*x0 + acc[1]*x1 + acc[2]*x2  + acc[9];
        float o1 = acc[3]*x0 + acc[4]*x1 + acc[5]*x2  + acc[10];
        float o2 = acc[6]*x0 + acc[7]*x1 + acc[8]*x2  + acc[11];
        float* op = out + ((size_t)b * Vv + v) * 3;
        op[0] = o0; op[1] = o1; op[2] = o2;
    }
}

extern "C" void kernel_launch(void* const* d_in, const int* in_sizes, int n_in,
                              void* d_out, int out_size, void* d_ws, size_t ws_size,
                              hipStream_t stream) {
    const float* X   = (const float*)d_in[0];  // (B,V,3) fp32
    const float* Vn  = (const float*)d_in[1];  // (B,C,3) fp32
    const float* r6  = (const float*)d_in[2];  // (B,C,6) fp32
    const float* W   = (const float*)d_in[3];  // (V,C)   fp32
    const int*   idx = (const int*)d_in[4];    // (C,)    int32
    float* out = (float*)d_out;                // (B,V,3) fp32
    float* A = (float*)d_ws;                   // B*C*12 floats = 30720 B

    precompute_A<<<(Bv * Cv + 255) / 256, 256, 0, stream>>>(X, Vn, r6, idx, A);
    deform_main<<<(Vv + 63) / 64, 256, 0, stream>>>(X, W, A, out);
}